// Round 3
// baseline (222.342 us; speedup 1.0000x reference)
//
#include <hip/hip_runtime.h>
#include <hip/hip_bf16.h>
#include <math.h>

// B,T,D,H = 64,2048,256,5
constexpr int BB   = 64;
constexpr int TT   = 2048;
constexpr int DD   = 256;
constexpr int HH   = 5;
constexpr int SEG  = 64;             // segments per batch row
constexpr int TSEG = TT / SEG;       // 32 timesteps per block
constexpr int PSTR = 264;            // partial row stride (floats), 1056B = 66*16 aligned
constexpr int WSTR = 264;            // ldsw slot stride (floats)

// fast tanh: 1 - 2/(e^{2x}+1). |err| ~1e-6, threshold is 1.7e-3.
__device__ __forceinline__ float ftanh(float x) {
    float e = __expf(2.0f * x);
    return 1.0f - 2.0f * __builtin_amdgcn_rcpf(e + 1.0f);
}

// One block = (b, 32-timestep segment). x kept in registers end-to-end:
// stage 8 floats/lane/row-group, dot -> 32-lane butterfly -> intermed,
// then weighted accumulation from the SAME registers. No online rescale
// needed (single chunk); cross-segment merge via (m,l,acc) partials.
__global__ __launch_bounds__(256, 3)
void seg_kernel(const float* __restrict__ x_temp,
                const float* __restrict__ x_fea,
                const int* __restrict__ mask,            // bool -> int32 per harness
                const float* __restrict__ W_temp,        // (D,H) row-major
                const float* __restrict__ b_temp,
                const float* __restrict__ W_fea,         // (1,H)
                const float* __restrict__ b_fea,
                const float* __restrict__ uw,            // (H,H)
                float* __restrict__ part)                // (B*SEG, PSTR)
{
    __shared__ alignas(16) float im[2 * TSEG];   // interleaved {intermed, maskf} per row
    __shared__ alignas(16) float ldsw[8 * WSTR]; // per-(wave,half) acc slot partials

    const int tid  = threadIdx.x;
    const int l    = tid & 63;
    const int wave = tid >> 6;
    const int half = l >> 5;
    const int l32  = l & 31;
    const int blk  = blockIdx.x;
    const int b    = blk >> 6;          // blk / SEG
    const int seg  = blk & (SEG - 1);
    const int t0   = seg * TSEG;
    const size_t rowbase = (size_t)b * TT;
    const float* xbase = x_temp + (rowbase + t0) * (size_t)DD;

    // mask -> odd slots of im (before barrier 1)
    if (tid < TSEG) im[2 * tid + 1] = mask[rowbase + t0 + tid] ? 1.0f : 0.0f;

    // ---- stage: 4 row-groups x 8 floats per lane, straight into registers ----
    // flat float offset = it*2048 + wave*512 + half*256 + l32*8  (bijective over 32x256)
    const int dbase = l32 * 8;
    float4 xq[4][2];
#pragma unroll
    for (int it = 0; it < 4; ++it) {
        const float* p = xbase + it * (8 * DD) + wave * (2 * DD) + half * DD + dbase;
        xq[it][0] = *(const float4*)(p);
        xq[it][1] = *(const float4*)(p + 4);
    }

    // per-lane W columns for its 8 d's (40 regs, reused by all 4 rows)
    float wv[8][HH];
#pragma unroll
    for (int e = 0; e < 8; ++e)
#pragma unroll
        for (int h = 0; h < HH; ++h)
            wv[e][h] = W_temp[(dbase + e) * HH + h];

    float wfea[HH], bfea[HH], btmp[HH], uwr[HH];
#pragma unroll
    for (int h = 0; h < HH; ++h) {
        wfea[h] = W_fea[h]; bfea[h] = b_fea[h]; btmp[h] = b_temp[h];
        float s = 0.f;
#pragma unroll
        for (int h2 = 0; h2 < HH; ++h2) s += uw[h * HH + h2];
        uwr[h] = s;  // sum(hadamard@uw+b,-1) = hadamard.uwr + const (cancels in softmax)
    }

    // ---- dot + 32-lane reduce + intermed, one row per (it,wave,half) ----
#pragma unroll
    for (int it = 0; it < 4; ++it) {
        const int r = it * 8 + wave * 2 + half;   // row in tile
        const float4 a0 = xq[it][0], a1 = xq[it][1];
        float ph[HH];
#pragma unroll
        for (int h = 0; h < HH; ++h)
            ph[h] = a0.x * wv[0][h] + a0.y * wv[1][h] + a0.z * wv[2][h] + a0.w * wv[3][h]
                  + a1.x * wv[4][h] + a1.y * wv[5][h] + a1.z * wv[6][h] + a1.w * wv[7][h];
#pragma unroll
        for (int off = 16; off >= 1; off >>= 1)
#pragma unroll
            for (int h = 0; h < HH; ++h)
                ph[h] += __shfl_xor(ph[h], off);   // stays within the 32-lane half

        const float xf = x_fea[rowbase + t0 + r];
        float inter = 0.f;
#pragma unroll
        for (int h = 0; h < HH; ++h)
            inter += ftanh(ph[h] + btmp[h]) * ftanh(xf * wfea[h] + bfea[h]) * uwr[h];
        if (l32 == 0) im[2 * r] = inter;
    }
    __syncthreads();

    // ---- softmax stats over the 32 rows (b128 broadcast reads, two passes) ----
    float M = -INFINITY;
#pragma unroll
    for (int k = 0; k < 16; ++k) {
        float4 v = *(const float4*)(&im[4 * k]);   // {i_2k, m_2k, i_2k+1, m_2k+1}
        M = fmaxf(M, fmaxf(v.x, v.z));
    }
    float lsum = 0.f;
#pragma unroll
    for (int k = 0; k < 16; ++k) {
        float4 v = *(const float4*)(&im[4 * k]);
        lsum += v.y * __expf(v.x - M) + v.w * __expf(v.z - M);
    }

    // ---- weighted accumulation from registers (lane's 4 rows, 8 d's) ----
    float acc8[8] = {0.f, 0.f, 0.f, 0.f, 0.f, 0.f, 0.f, 0.f};
#pragma unroll
    for (int it = 0; it < 4; ++it) {
        const int r = it * 8 + wave * 2 + half;
        const float w = im[2 * r + 1] * __expf(im[2 * r] - M);
        const float4 a0 = xq[it][0], a1 = xq[it][1];
        acc8[0] = fmaf(w, a0.x, acc8[0]); acc8[1] = fmaf(w, a0.y, acc8[1]);
        acc8[2] = fmaf(w, a0.z, acc8[2]); acc8[3] = fmaf(w, a0.w, acc8[3]);
        acc8[4] = fmaf(w, a1.x, acc8[4]); acc8[5] = fmaf(w, a1.y, acc8[5]);
        acc8[6] = fmaf(w, a1.z, acc8[6]); acc8[7] = fmaf(w, a1.w, acc8[7]);
    }

    // ---- merge 8 (wave,half) slots via LDS ----
    const int slot = wave * 2 + half;
    float* wp = &ldsw[slot * WSTR + dbase];
    *(float4*)(wp)     = make_float4(acc8[0], acc8[1], acc8[2], acc8[3]);
    *(float4*)(wp + 4) = make_float4(acc8[4], acc8[5], acc8[6], acc8[7]);
    __syncthreads();

    float accd = 0.f;
#pragma unroll
    for (int s = 0; s < 8; ++s) accd += ldsw[s * WSTR + tid];

    float* pb = part + (size_t)blk * PSTR;
    if (tid == 0) pb[0] = M;
    if (tid == 1) pb[1] = lsum;
    pb[2 + tid] = accd;
}

// Merge SEG partials per batch row.
__global__ __launch_bounds__(256)
void combine_kernel(const float* __restrict__ part, float* __restrict__ out)
{
    const int b = blockIdx.x;
    const int d = threadIdx.x;
    const float* base = part + (size_t)b * SEG * PSTR;
    float M = -INFINITY;
#pragma unroll 8
    for (int s = 0; s < SEG; ++s)
        M = fmaxf(M, base[(size_t)s * PSTR]);
    float denom = 0.f, num = 0.f;
#pragma unroll 4
    for (int s = 0; s < SEG; ++s) {
        const float* p = base + (size_t)s * PSTR;
        float sc = __expf(p[0] - M);
        denom = fmaf(sc, p[1], denom);
        num   = fmaf(sc, p[2 + d], num);
    }
    out[(size_t)b * DD + d] = num / denom;
}

extern "C" void kernel_launch(void* const* d_in, const int* in_sizes, int n_in,
                              void* d_out, int out_size, void* d_ws, size_t ws_size,
                              hipStream_t stream) {
    const float* x_temp = (const float*)d_in[0];
    const float* x_fea  = (const float*)d_in[1];
    const int*   mask   = (const int*)d_in[2];
    const float* W_temp = (const float*)d_in[3];
    const float* b_temp = (const float*)d_in[4];
    const float* W_fea  = (const float*)d_in[5];
    const float* b_fea  = (const float*)d_in[6];
    // d_in[7] = b : constant across T, cancels in softmax — unused.
    const float* uw     = (const float*)d_in[8];

    float* part = (float*)d_ws;   // BB*SEG x PSTR floats ~ 4.3 MB
    float* out  = (float*)d_out;

    seg_kernel<<<BB * SEG, 256, 0, stream>>>(x_temp, x_fea, mask, W_temp,
                                             b_temp, W_fea, b_fea, uw, part);
    combine_kernel<<<BB, DD, 0, stream>>>(part, out);
}